// Round 10
// baseline (407.084 us; speedup 1.0000x reference)
//
#include <hip/hip_runtime.h>

#define HSZ 32
#define SEQ 1024

typedef float v2f __attribute__((ext_vector_type(2)));

__device__ __forceinline__ float fast_rcp(float v) { return __builtin_amdgcn_rcpf(v); }

// sigmoid(x) = 1/(1+exp(-x)); exp args bounded (|g| <~ 10), rcp(inf)=0 saturation safe.
__device__ __forceinline__ float sigmoidf_(float v) {
    return fast_rcp(1.0f + __expf(-v));
}
__device__ __forceinline__ float tanhf_(float v) {
    return fmaf(2.0f, sigmoidf_(2.0f * v), -1.0f);
}

// r10: ONE batch per wave, 2 gate rows per lane (64 weight scalars/lane), so the
// full working set (~135 regs) fits the 256-VGPR budget at 2 waves/SIMD with no
// AGPR parking (r6-r9: ~200 hidden accvgpr copies/step). 2048 waves = 2/SIMD;
// the second wave on each SIMD hides the recurrence-chain stalls.
// Low lanes (u<32) own rows u (i), u+32 (f); high lanes own u+64 (g), u+96 (o).
// Gate exchange: one shfl_xor(32) pair. Single-wave blocks -> no barriers
// (DS pipe is in-order per wave).
__global__ __launch_bounds__(64)
__attribute__((amdgpu_waves_per_eu(2, 2)))
void lstm_attn_fused(const float* __restrict__ x,
                     const float* __restrict__ W_ih,
                     const float* __restrict__ W_hh,
                     const float* __restrict__ b_ih,
                     const float* __restrict__ b_hh,
                     const float* __restrict__ attn_w,
                     const float* __restrict__ fc1_w,
                     const float* __restrict__ fc1_b,
                     const float* __restrict__ fc2_w,
                     const float* __restrict__ fc2_b,
                     float* __restrict__ out)
{
    const int lane = threadIdx.x;        // 0..63
    const int u    = lane & 31;          // hidden unit owned by this lane
    const bool low = lane < 32;
    const int b    = blockIdx.x;         // batch element
    const int r0   = u + (low ? 0 : 64); // row of gate A (i or g)
    const int r1   = r0 + 32;            // row of gate B (f or o)

    // ---- preload weights: 2 gate rows per lane, v2 packed for v_pk_fma_f32 ----
    const v2f* __restrict__ Whv = (const v2f*)W_hh;      // [128][16] v2f
    v2f w0[16], w1[16];
#pragma unroll
    for (int k = 0; k < 16; ++k) {
        w0[k] = Whv[r0 * 16 + k];
        w1[k] = Whv[r1 * 16 + k];
    }
    float wi0[3], wi1[3];
#pragma unroll
    for (int j = 0; j < 3; ++j) {
        wi0[j] = W_ih[r0 * 3 + j];
        wi1[j] = W_ih[r1 * 3 + j];
    }
    float b0 = b_ih[r0] + b_hh[r0];
    float b1 = b_ih[r1] + b_hh[r1];
    float aw = attn_w[u];

    // Pin loop-invariants (asm defs can't be rematerialized from memory).
#pragma unroll
    for (int k = 0; k < 16; ++k) {
        asm volatile("" : "+v"(w0[k]), "+v"(w1[k]));
    }
#pragma unroll
    for (int j = 0; j < 3; ++j) {
        asm volatile("" : "+v"(wi0[j]), "+v"(wi1[j]));
    }
    asm volatile("" : "+v"(b0), "+v"(b1), "+v"(aw));

    // gate-A nonlinearity: low -> sigmoid(i); high -> tanh(g) = 2*sigmoid(2x)-1
    const float nsS = low ? 1.0f : 2.0f;
    const float nsA = low ? 1.0f : 2.0f;
    const float nsB = low ? 0.0f : -1.0f;

    // h state: slots 0..31 authoritative (written by low half); broadcast reads.
    __shared__ float hbuf[64];
    hbuf[lane] = 0.0f;
    const v2f* __restrict__ hb2 = (const v2f*)hbuf;

    float c = 0.0f, h = 0.0f;
    float Pacc = 0.0f, lacc = 0.0f;      // online softmax pooling (scores bounded ~5.7)

    const float4* __restrict__ xv = (const float4*)(x + (size_t)b * SEQ * 3);

    // hp regs hold h_{t-1}; h0 = 0 (no LDS read needed for step 1).
    v2f hp[16];
#pragma unroll
    for (int k = 0; k < 16; ++k) { hp[k].x = 0.0f; hp[k].y = 0.0f; }

    auto step = [&](float x0, float x1, float x2) {
        // input projection
        v2f a00; a00.x = fmaf(wi0[0],x0, fmaf(wi0[1],x1, fmaf(wi0[2],x2, b0))); a00.y = 0.0f;
        v2f a10; a10.x = fmaf(wi1[0],x0, fmaf(wi1[1],x1, fmaf(wi1[2],x2, b1))); a10.y = 0.0f;
        v2f a01 = {0.0f, 0.0f}, a11 = {0.0f, 0.0f};

        // matvec: two independent 8-deep pk-FMA chains per gate row
#pragma unroll
        for (int k = 0; k < 8; ++k) {
            a00 = __builtin_elementwise_fma(w0[k],     hp[k],     a00);
            a01 = __builtin_elementwise_fma(w0[k + 8], hp[k + 8], a01);
            a10 = __builtin_elementwise_fma(w1[k],     hp[k],     a10);
            a11 = __builtin_elementwise_fma(w1[k + 8], hp[k + 8], a11);
        }
        const v2f s0 = a00 + a01;
        const v2f s1 = a10 + a11;

        // nonlinearities: v0 = i (low) / g (high); v1 = f (low) / o (high)
        const float v0 = fmaf(nsA, sigmoidf_(nsS * (s0.x + s0.y)), nsB);
        const float v1 = sigmoidf_(s1.x + s1.y);

        // exchange with the partner half (one xor-32 pair)
        const float e0 = __shfl_xor(v0, 32);
        const float e1 = __shfl_xor(v1, 32);
        const float i_ = low ? v0 : e0;
        const float f_ = low ? v1 : e1;
        const float g_ = low ? e0 : v0;
        const float o_ = low ? e1 : v1;

        c = fmaf(f_, c, i_ * g_);
        h = o_ * tanhf_(c);              // both halves hold identical h of unit u

        hbuf[lane] = h;                  // low half's writes (slots 0..31) are the state

        // prefetch h_t for the NEXT step (in-order DS: reads see the write; no fence)
#pragma unroll
        for (int k = 0; k < 16; ++k) hp[k] = hb2[k];

        // attention tail on h_t (off the recurrence chain; overlapped by the other wave)
        float p = h * aw;
        p += __int_as_float(__builtin_amdgcn_ds_swizzle(__float_as_int(p), 0x041F)); // xor 1
        p += __int_as_float(__builtin_amdgcn_ds_swizzle(__float_as_int(p), 0x081F)); // xor 2
        p += __int_as_float(__builtin_amdgcn_ds_swizzle(__float_as_int(p), 0x101F)); // xor 4
        p += __int_as_float(__builtin_amdgcn_ds_swizzle(__float_as_int(p), 0x201F)); // xor 8
        p += __int_as_float(__builtin_amdgcn_ds_swizzle(__float_as_int(p), 0x401F)); // xor 16
        const float wgt = __expf(fmaxf(p, 0.0f));
        lacc += wgt;
        Pacc = fmaf(wgt, h, Pacc);
    };

    // x software pipeline: prefetch next 4-step group while computing current
    float4 xa = xv[0], xb = xv[1], xc = xv[2];
    for (int s0 = 0; s0 < SEQ; s0 += 4) {
        const int nfi = ((s0 + 4) < SEQ) ? (((s0 + 4) * 3) >> 2) : 0;
        const float4 na = xv[nfi], nb = xv[nfi + 1], nc = xv[nfi + 2];
        step(xa.x, xa.y, xa.z);
        step(xa.w, xb.x, xb.y);
        step(xb.z, xb.w, xc.x);
        step(xc.y, xc.z, xc.w);
        xa = na; xb = nb; xc = nc;
    }

    // ---- epilogue: pooled -> fc1(relu) -> fc2 (single-wave, no barriers) ----
    hbuf[lane] = Pacc * fast_rcp(lacc);  // pooled[u] in slots 0..31

    {
        const int j = lane & 15;         // fc1 row (computed redundantly by 4 lanes)
        float acc = fc1_b[j];
#pragma unroll
        for (int k = 0; k < HSZ; ++k)
            acc = fmaf(fc1_w[j * HSZ + k], hbuf[k], acc);
        __shared__ float h1sh[16];
        if (lane < 16) h1sh[j] = fmaxf(acc, 0.0f);

        if (lane < 2) {
            float acc2 = fc2_b[lane];
#pragma unroll
            for (int m = 0; m < 16; ++m)
                acc2 = fmaf(fc2_w[lane * 16 + m], h1sh[m], acc2);
            out[b * 2 + lane] = acc2;
        }
    }
}

extern "C" void kernel_launch(void* const* d_in, const int* in_sizes, int n_in,
                              void* d_out, int out_size, void* d_ws, size_t ws_size,
                              hipStream_t stream) {
    const float* x      = (const float*)d_in[0];
    const float* W_ih   = (const float*)d_in[1];
    const float* W_hh   = (const float*)d_in[2];
    const float* b_ih   = (const float*)d_in[3];
    const float* b_hh   = (const float*)d_in[4];
    const float* attn_w = (const float*)d_in[5];
    const float* fc1_w  = (const float*)d_in[6];
    const float* fc1_b  = (const float*)d_in[7];
    const float* fc2_w  = (const float*)d_in[8];
    const float* fc2_b  = (const float*)d_in[9];

    const int B = in_sizes[0] / (SEQ * 3);   // 2048

    lstm_attn_fused<<<dim3(B), dim3(64), 0, stream>>>(
        x, W_ih, W_hh, b_ih, b_hh, attn_w, fc1_w, fc1_b, fc2_w, fc2_b,
        (float*)d_out);
}